// Round 4
// baseline (836.363 us; speedup 1.0000x reference)
//
#include <hip/hip_runtime.h>

// Inverse Haar DWT, fp32. Input: 4 subbands (B,C,H2,W2)=(8,64,256,256).
// Output: (B,C,2*H2,2*W2). Each half-res pixel (ll,lh,hl,hh) -> 2x2 block:
//   a = .5*(ll-lh-hl+hh)  b = .5*(ll-lh+hl-hh)
//   c = .5*(ll+lh-hl-hh)  d = .5*(ll+lh+hl+hh)
// Memory-bound: 1 GiB total traffic/call. Roofline @6.3 TB/s ~= 170 us.
//
// One thread per float4 of half-res pixels: 4x16B coalesced loads, 4x16B
// stores into two contiguous output rows (a wave covers one full half-res
// row: 64 lanes * 4 elems = 256 = W2, so loads are perfect 1 KiB/instr and
// stores cover two contiguous 2 KiB output rows per wave).
// (resubmit r3: rounds 0-2 failed in container acquisition/infra, not code)

static constexpr int kH2 = 256;
static constexpr int kW2 = 256;
static constexpr int kW  = 2 * kW2;   // 512
static constexpr int kU  = kW2 / 4;   // float4 units per half-res row = 64

__global__ __launch_bounds__(256) void idwt_haar_kernel(
    const float4* __restrict__ ll, const float4* __restrict__ lh,
    const float4* __restrict__ hl, const float4* __restrict__ hh,
    float4* __restrict__ out, int n4)
{
    for (int t = blockIdx.x * blockDim.x + threadIdx.x; t < n4;
         t += gridDim.x * blockDim.x) {

        int row = t >> 6;            // half-res row index over B*C*H2
        int u   = t & (kU - 1);      // float4 unit within the row
        int i   = row & (kH2 - 1);   // half-res row within one (b,c) image
        int bc  = row >> 8;          // b*C + c

        float4 vll = ll[t], vlh = lh[t], vhl = hl[t], vhh = hh[t];

        float L[4]  = {vll.x, vll.y, vll.z, vll.w};
        float Hh[4] = {vlh.x, vlh.y, vlh.z, vlh.w};
        float V[4]  = {vhl.x, vhl.y, vhl.z, vhl.w};
        float D[4]  = {vhh.x, vhh.y, vhh.z, vhh.w};

        float a[4], b[4], c[4], d[4];
#pragma unroll
        for (int k = 0; k < 4; ++k) {
            float s0 = L[k] + D[k];   // ll + hh
            float s1 = L[k] - D[k];   // ll - hh
            float s2 = Hh[k] + V[k];  // lh + hl
            float s3 = Hh[k] - V[k];  // lh - hl
            a[k] = 0.5f * (s0 - s2);  // ll - lh - hl + hh
            b[k] = 0.5f * (s1 - s3);  // ll - lh + hl - hh
            c[k] = 0.5f * (s1 + s3);  // ll + lh - hl - hh
            d[k] = 0.5f * (s0 + s2);  // ll + lh + hl + hh
        }

        // Output: rows 2i and 2i+1 of image bc, columns 8u .. 8u+7.
        size_t obase4 =
            ((size_t)bc * (2 * kH2) + 2 * (size_t)i) * (kW / 4) + 2 * (size_t)u;
        out[obase4]                = make_float4(a[0], b[0], a[1], b[1]);
        out[obase4 + 1]            = make_float4(a[2], b[2], a[3], b[3]);
        out[obase4 + (kW / 4)]     = make_float4(c[0], d[0], c[1], d[1]);
        out[obase4 + (kW / 4) + 1] = make_float4(c[2], d[2], c[3], d[3]);
    }
}

extern "C" void kernel_launch(void* const* d_in, const int* in_sizes, int n_in,
                              void* d_out, int out_size, void* d_ws, size_t ws_size,
                              hipStream_t stream) {
    const float4* ll = (const float4*)d_in[0];
    const float4* lh = (const float4*)d_in[1];
    const float4* hl = (const float4*)d_in[2];
    const float4* hh = (const float4*)d_in[3];
    float4* out = (float4*)d_out;

    int n4 = in_sizes[0] / 4;          // 8*64*256*256/4 = 1,048,576 threads
    int block = 256;
    int grid = (n4 + block - 1) / block;
    idwt_haar_kernel<<<grid, block, 0, stream>>>(ll, lh, hl, hh, out, n4);
}

// Round 5
// 803.643 us; speedup vs baseline: 1.0407x; 1.0407x over previous
//
#include <hip/hip_runtime.h>

// Inverse Haar DWT, fp32. Input: 4 subbands (B,C,H2,W2)=(8,64,256,256).
// Output: (B,C,2*H2,2*W2). Each half-res pixel (ll,lh,hl,hh) -> 2x2 block:
//   a = .5*(ll-lh-hl+hh)  b = .5*(ll-lh+hl-hh)
//   c = .5*(ll+lh-hl-hh)  d = .5*(ll+lh+hl+hh)
// Memory-bound: 1 GiB total traffic/call. Roofline @6.3 TB/s ~= 170 us.
//
// r4 redesign: one thread per float2 of half-res pixels.
//  - loads: 4x 8B contiguous per lane (512B/wave/instr, zero redundancy)
//  - stores: 2x 16B contiguous per lane (1KiB/wave/instr, full-line coverage)
//    -> every store instruction is perfectly coalesced (prev version wrote
//       16B/lane at 32B stride, half-lines per instruction)
//  - nontemporal hints: every byte touched exactly once; keep L2 clean.

typedef float f32x2 __attribute__((ext_vector_type(2)));
typedef float f32x4 __attribute__((ext_vector_type(4)));

__global__ __launch_bounds__(256) void idwt_haar_kernel(
    const f32x2* __restrict__ ll, const f32x2* __restrict__ lh,
    const f32x2* __restrict__ hl, const f32x2* __restrict__ hh,
    f32x4* __restrict__ out, int n2)
{
    for (int t = blockIdx.x * blockDim.x + threadIdx.x; t < n2;
         t += gridDim.x * blockDim.x) {

        // t linearizes (bc, i, v): v = float2 unit in row (128/row),
        // i = half-res row (256/image), bc = b*C + c.
        int v = t & 127;

        f32x2 L = __builtin_nontemporal_load(ll + t);
        f32x2 Hx = __builtin_nontemporal_load(lh + t);
        f32x2 V = __builtin_nontemporal_load(hl + t);
        f32x2 D = __builtin_nontemporal_load(hh + t);

        f32x2 s0 = L + D;   // ll + hh
        f32x2 s1 = L - D;   // ll - hh
        f32x2 s2 = Hx + V;  // lh + hl
        f32x2 s3 = Hx - V;  // lh - hl

        f32x2 a = 0.5f * (s0 - s2);  // ll - lh - hl + hh  (top-left)
        f32x2 b = 0.5f * (s1 - s3);  // ll - lh + hl - hh  (top-right)
        f32x2 c = 0.5f * (s1 + s3);  // ll + lh - hl - hh  (bottom-left)
        f32x2 d = 0.5f * (s0 + s2);  // ll + lh + hl + hh  (bottom-right)

        f32x4 top = {a.x, b.x, a.y, b.y};   // row 2i,   cols 4v..4v+3
        f32x4 bot = {c.x, d.x, c.y, d.y};   // row 2i+1, cols 4v..4v+3

        // out float4 index: top = (bc*512 + 2i)*128 + v = 2t - v; bot = +128.
        size_t otop = 2 * (size_t)t - (size_t)v;
        __builtin_nontemporal_store(top, out + otop);
        __builtin_nontemporal_store(bot, out + otop + 128);
    }
}

extern "C" void kernel_launch(void* const* d_in, const int* in_sizes, int n_in,
                              void* d_out, int out_size, void* d_ws, size_t ws_size,
                              hipStream_t stream) {
    const f32x2* ll = (const f32x2*)d_in[0];
    const f32x2* lh = (const f32x2*)d_in[1];
    const f32x2* hl = (const f32x2*)d_in[2];
    const f32x2* hh = (const f32x2*)d_in[3];
    f32x4* out = (f32x4*)d_out;

    int n2 = in_sizes[0] / 2;          // 8*64*256*256/2 = 16,777,216 threads
    int block = 256;
    int grid = (n2 + block - 1) / block;   // 65536 blocks
    idwt_haar_kernel<<<grid, block, 0, stream>>>(ll, lh, hl, hh, out, n2);
}

// Round 7
// 799.850 us; speedup vs baseline: 1.0457x; 1.0047x over previous
//
#include <hip/hip_runtime.h>

// Inverse Haar DWT, fp32. Input: 4 subbands (B,C,H2,W2)=(8,64,256,256).
// Output: (B,C,2*H2,2*W2). Each half-res pixel (ll,lh,hl,hh) -> 2x2 block:
//   a = .5*(ll-lh-hl+hh)  b = .5*(ll-lh+hl-hh)
//   c = .5*(ll+lh-hl-hh)  d = .5*(ll+lh+hl+hh)
// Memory-bound: 1 GiB total traffic/call. Roofline @6.3 TB/s ~= 170 us.
//
// r6 (resubmit r7 — r6 hit GPUAcquisitionTimeout, never ran): two
// wave-strided float2 units per thread (j and j+64 of the same half-res
// row). Every load instruction covers 512B contiguous per wave, every
// store instruction covers 1KiB contiguous per wave (full 64B lines).
// Per-byte address/loop VALU work halves vs r5. Nontemporal on both sides
// (each byte touched exactly once).

typedef float f32x2 __attribute__((ext_vector_type(2)));
typedef float f32x4 __attribute__((ext_vector_type(4)));

__device__ __forceinline__ void haar2(const f32x2& L, const f32x2& Hx,
                                      const f32x2& V, const f32x2& D,
                                      f32x4& top, f32x4& bot)
{
    f32x2 s0 = L + D;   // ll + hh
    f32x2 s1 = L - D;   // ll - hh
    f32x2 s2 = Hx + V;  // lh + hl
    f32x2 s3 = Hx - V;  // lh - hl
    f32x2 a = 0.5f * (s0 - s2);  // top-left
    f32x2 b = 0.5f * (s1 - s3);  // top-right
    f32x2 c = 0.5f * (s1 + s3);  // bottom-left
    f32x2 d = 0.5f * (s0 + s2);  // bottom-right
    top = f32x4{a.x, b.x, a.y, b.y};
    bot = f32x4{c.x, d.x, c.y, d.y};
}

__global__ __launch_bounds__(256) void idwt_haar_kernel(
    const f32x2* __restrict__ ll, const f32x2* __restrict__ lh,
    const f32x2* __restrict__ hl, const f32x2* __restrict__ hh,
    f32x4* __restrict__ out, int np)
{
    int tt = blockIdx.x * blockDim.x + threadIdx.x;
    if (tt >= np) return;

    int row = tt >> 6;           // half-res row index over B*C*H2
    int j   = tt & 63;           // lane-aligned: wave covers one half-row pair
    int u0  = (row << 7) + j;    // float2 unit j   of row (128 units/row)
    int u1  = u0 + 64;           // float2 unit j+64

    f32x2 L0 = __builtin_nontemporal_load(ll + u0);
    f32x2 L1 = __builtin_nontemporal_load(ll + u1);
    f32x2 H0 = __builtin_nontemporal_load(lh + u0);
    f32x2 H1 = __builtin_nontemporal_load(lh + u1);
    f32x2 V0 = __builtin_nontemporal_load(hl + u0);
    f32x2 V1 = __builtin_nontemporal_load(hl + u1);
    f32x2 D0 = __builtin_nontemporal_load(hh + u0);
    f32x2 D1 = __builtin_nontemporal_load(hh + u1);

    f32x4 top0, bot0, top1, bot1;
    haar2(L0, H0, V0, D0, top0, bot0);
    haar2(L1, H1, V1, D1, top1, bot1);

    // Output float4 index of top row for unit u0: row*256 + j.
    // Unit u1 lands at +64; bottom row at +128.
    size_t otop = ((size_t)row << 8) + (size_t)j;
    __builtin_nontemporal_store(top0, out + otop);
    __builtin_nontemporal_store(top1, out + otop + 64);
    __builtin_nontemporal_store(bot0, out + otop + 128);
    __builtin_nontemporal_store(bot1, out + otop + 192);
}

extern "C" void kernel_launch(void* const* d_in, const int* in_sizes, int n_in,
                              void* d_out, int out_size, void* d_ws, size_t ws_size,
                              hipStream_t stream) {
    const f32x2* ll = (const f32x2*)d_in[0];
    const f32x2* lh = (const f32x2*)d_in[1];
    const f32x2* hl = (const f32x2*)d_in[2];
    const f32x2* hh = (const f32x2*)d_in[3];
    f32x4* out = (f32x4*)d_out;

    int np = in_sizes[0] / 4;          // thread count: 8*64*256*256/4 = 8,388,608
    int block = 256;
    int grid = (np + block - 1) / block;   // 32768 blocks
    idwt_haar_kernel<<<grid, block, 0, stream>>>(ll, lh, hl, hh, out, np);
}